// Round 1
// 268.907 us; speedup vs baseline: 1.1506x; 1.1506x over previous
//
#include <hip/hip_runtime.h>
#include <hip/hip_bf16.h>

#define B_SZ 16
#define C_IN 256
#define N_SP 2304
#define K_INT 128
#define NTILE 36  // q-tiles of 64
#define MT 32     // key/value m-tile
#define MITER 72  // N_SP / MT

typedef __attribute__((ext_vector_type(8))) short short8;
typedef __attribute__((ext_vector_type(4))) float f32x4;

// packed fp32x2 -> bf16x2 (v_cvt_pk_bf16_f32, RNE)
__device__ inline unsigned pk_bf16(float a, float b) {
  float2 f; f.x = a; f.y = b;
  __hip_bfloat162 h = __float22bfloat162_rn(f);
  unsigned u;
  __builtin_memcpy(&u, &h, sizeof(u));
  return u;
}

// ---------------------------------------------------------------------------
// Projection: Qt[b][n][k], Kt[b][n][k] (bf16), Gbf[b][c][n] = bf16(x).
// (unchanged from previous round)
// ---------------------------------------------------------------------------
__global__ __launch_bounds__(256) void proj_kernel(
    const float* __restrict__ x,
    const float* __restrict__ theta_w, const float* __restrict__ theta_b,
    const float* __restrict__ phi_w,   const float* __restrict__ phi_b,
    short* __restrict__ Qt, short* __restrict__ Kt, short* __restrict__ Gbf)
{
  __shared__ short Xl[64][264];  // [n][c], +8 pad

  const int b  = blockIdx.x / NTILE;
  const int n0 = (blockIdx.x % NTILE) * 64;
  const int t  = threadIdx.x;  // t == channel c for staging

  // ---- stage: read x row (64 fp32), packed-convert, write Gbf + LDS T ----
  {
    const float* xrow = x + ((size_t)b * C_IN + t) * N_SP + n0;
    unsigned tp[32];
#pragma unroll
    for (int i = 0; i < 16; ++i) {
      float4 v = ((const float4*)xrow)[i];
      tp[2*i]   = pk_bf16(v.x, v.y);
      tp[2*i+1] = pk_bf16(v.z, v.w);
    }
    uint4* grow = (uint4*)(Gbf + ((size_t)b * C_IN + t) * N_SP + n0);
#pragma unroll
    for (int i = 0; i < 8; ++i) {
      uint4 u; u.x = tp[4*i]; u.y = tp[4*i+1]; u.z = tp[4*i+2]; u.w = tp[4*i+3];
      grow[i] = u;
    }
#pragma unroll
    for (int j = 0; j < 32; ++j) {
      Xl[2*j][t]   = (short)tp[j];
      Xl[2*j+1][t] = (short)(tp[j] >> 16);
    }
  }
  __syncthreads();

  const int wave = t >> 6, lane = t & 63;
  const int col = lane & 15, quad = lane >> 4;

  f32x4 acc[2][2][4];
#pragma unroll
  for (int p = 0; p < 2; ++p)
#pragma unroll
    for (int kr = 0; kr < 2; ++kr)
#pragma unroll
      for (int j = 0; j < 4; ++j) {
        acc[p][kr][j][0] = 0.f; acc[p][kr][j][1] = 0.f;
        acc[p][kr][j][2] = 0.f; acc[p][kr][j][3] = 0.f;
      }

#pragma unroll
  for (int cs = 0; cs < 8; ++cs) {
    const int c0 = cs * 32;
    short8 afr[2][2];
#pragma unroll
    for (int p = 0; p < 2; ++p) {
      const float* W = p ? phi_w : theta_w;
#pragma unroll
      for (int kr = 0; kr < 2; ++kr) {
        const int k = wave * 32 + kr * 16 + col;
        const float* wp = W + (size_t)k * C_IN + c0 + quad * 8;
        float4 w0 = ((const float4*)wp)[0];
        float4 w1 = ((const float4*)wp)[1];
        unsigned u[4];
        u[0] = pk_bf16(w0.x, w0.y); u[1] = pk_bf16(w0.z, w0.w);
        u[2] = pk_bf16(w1.x, w1.y); u[3] = pk_bf16(w1.z, w1.w);
        short8 a;
        __builtin_memcpy(&a, u, sizeof(a));
        afr[p][kr] = a;
      }
    }
#pragma unroll
    for (int j = 0; j < 4; ++j) {
      short8 bfr = *(const short8*)&Xl[j * 16 + col][c0 + quad * 8];
#pragma unroll
      for (int p = 0; p < 2; ++p)
#pragma unroll
        for (int kr = 0; kr < 2; ++kr)
          acc[p][kr][j] = __builtin_amdgcn_mfma_f32_16x16x32_bf16(
              afr[p][kr], bfr, acc[p][kr][j], 0, 0, 0);
    }
  }

  // ---- epilogue: bias + transpose-store to [b][n][k] bf16 ----
#pragma unroll
  for (int p = 0; p < 2; ++p) {
    const float* bias = p ? phi_b : theta_b;
    short* dst = p ? Kt : Qt;
#pragma unroll
    for (int kr = 0; kr < 2; ++kr) {
      const int k0 = wave * 32 + kr * 16 + quad * 4;
      float4 bv = *(const float4*)(bias + k0);
#pragma unroll
      for (int j = 0; j < 4; ++j) {
        const int n = n0 + j * 16 + col;
        f32x4 v = acc[p][kr][j];
        uint2 sv;
        sv.x = pk_bf16(v[0] + bv.x, v[1] + bv.y);
        sv.y = pk_bf16(v[2] + bv.z, v[3] + bv.w);
        *(uint2*)(dst + ((size_t)b * N_SP + n) * K_INT + k0) = sv;
      }
    }
  }
}

// ---------------------------------------------------------------------------
// Flash attention, m-tile 32.
//  - swapped QK^T (A=K): P lands at lane col=q; permlane{32,16}_swap builds
//    the PV A-fragment fully in registers (no Pl LDS round-trip, no shfl)
//  - l_i accumulated by an extra ones-column MFMA (epilogue-ready layout)
//  - XOR-swizzled pad-free K/G tiles (conflict-free b128 reads+writes)
//  - double-buffered LDS (A at +0, B at +24576), ONE barrier per iter
// ---------------------------------------------------------------------------
__global__ __launch_bounds__(256) void attn_kernel(
    const short* __restrict__ Qt, const short* __restrict__ Kt,
    const short* __restrict__ Gbf, float* __restrict__ out)
{
  // layout (bytes): A: K[0,8192) G[8192,24576) | B: K[24576,32768) G[32768,49152)
  __shared__ __align__(16) char smem[49152];

  const int b   = blockIdx.x / NTILE;
  const int qn0 = (blockIdx.x % NTILE) * 64;
  const int t = threadIdx.x;
  const int wave = t >> 6, lane = t & 63;
  const int col = lane & 15, quad = lane >> 4;

  const short* Ktb = Kt  + (size_t)b * N_SP * K_INT;
  const short* Gb  = Gbf + (size_t)b * C_IN * N_SP;

  // Q fragments in registers for the whole loop (B-operand layout: col=q)
  short8 qf[4];
  {
    const short* qb = Qt + ((size_t)b * N_SP + qn0 + wave * 16 + col) * K_INT + quad * 8;
#pragma unroll
    for (int kk = 0; kk < 4; ++kk) qf[kk] = *(const short8*)(qb + kk * 32);
  }

  f32x4 yacc[16];
#pragma unroll
  for (int i = 0; i < 16; ++i) {
    yacc[i][0] = 0.f; yacc[i][1] = 0.f; yacc[i][2] = 0.f; yacc[i][3] = 0.f;
  }
  f32x4 lacc;
  lacc[0] = 0.f; lacc[1] = 0.f; lacc[2] = 0.f; lacc[3] = 0.f;

  short8 ones;
#pragma unroll
  for (int j = 0; j < 8; ++j) ones[j] = (short)0x3F80;  // bf16 1.0

  const float SC2 = 0.12754859f;  // (1/sqrt(128)) * log2(e)

  // ---- LDS byte offsets (loop-invariant; swizzle folded into base) ----
  // K tile [32][128] bf16, 16B-chunk swizzle: phys = chunk ^ (row&7)
  const int KW = (t >> 4) * 256 + ((((t & 15) ^ ((t >> 4) & 7))) << 4);
  // G tile [256][32] bf16, 16B-chunk swizzle: phys = chunk ^ ((row>>1)&3)
  const int GW = 8192 + (t >> 2) * 64 + ((((t & 3) ^ ((t >> 3) & 3))) << 4);
  int KR[4];
#pragma unroll
  for (int kk = 0; kk < 4; ++kk)
    KR[kk] = col * 256 + ((((kk << 2) + quad) ^ (col & 7)) << 4);
  const int GR = 8192 + col * 64 + ((quad ^ ((col >> 1) & 3)) << 4);

  // ---- global staging offsets ----
  const int koff = (t >> 4) * K_INT + (t & 15) * 8;  // K rows t>>4 / +16
  const int goff = (t >> 2) * N_SP + (t & 3) * 8;    // G rows t>>2 (+64i)

  short8 pre[6];
  // stage tile 0 -> buffer A
  pre[0] = *(const short8*)(Ktb + koff);
  pre[1] = *(const short8*)(Ktb + 2048 + koff);
#pragma unroll
  for (int i = 0; i < 4; ++i) pre[2 + i] = *(const short8*)(Gb + i * 64 * N_SP + goff);
  *(short8*)(smem + KW) = pre[0];
  *(short8*)(smem + KW + 4096) = pre[1];
#pragma unroll
  for (int i = 0; i < 4; ++i) *(short8*)(smem + GW + i * 4096) = pre[2 + i];
  // issue tile 1 loads
  pre[0] = *(const short8*)(Ktb + 4096 + koff);
  pre[1] = *(const short8*)(Ktb + 6144 + koff);
#pragma unroll
  for (int i = 0; i < 4; ++i) pre[2 + i] = *(const short8*)(Gb + 32 + i * 64 * N_SP + goff);
  const short* kptr = Ktb + 8192 + koff;  // tile 2
  const short* gptr = Gb + 64 + goff;     // tile 2
  __syncthreads();

#define SUBITER(MTV, RD, WR)                                                   \
  {                                                                            \
    if ((MTV) + 1 < MITER) {                                                   \
      *(short8*)(smem + KW + (WR)) = pre[0];                                   \
      *(short8*)(smem + KW + (WR) + 4096) = pre[1];                            \
      _Pragma("unroll")                                                        \
      for (int i = 0; i < 4; ++i)                                              \
        *(short8*)(smem + GW + (WR) + i * 4096) = pre[2 + i];                  \
      if ((MTV) + 2 < MITER) {                                                 \
        pre[0] = *(const short8*)(kptr);                                       \
        pre[1] = *(const short8*)(kptr + 2048);                                \
        _Pragma("unroll")                                                      \
        for (int i = 0; i < 4; ++i)                                            \
          pre[2 + i] = *(const short8*)(gptr + i * 64 * N_SP);                 \
        kptr += 4096; gptr += 32;                                              \
      }                                                                        \
    }                                                                          \
    f32x4 s0, s1;                                                              \
    s0[0] = 0.f; s0[1] = 0.f; s0[2] = 0.f; s0[3] = 0.f;                        \
    s1[0] = 0.f; s1[1] = 0.f; s1[2] = 0.f; s1[3] = 0.f;                        \
    _Pragma("unroll")                                                          \
    for (int kk = 0; kk < 4; ++kk) {                                           \
      short8 a0 = *(const short8*)(smem + KR[kk] + (RD));                      \
      s0 = __builtin_amdgcn_mfma_f32_16x16x32_bf16(a0, qf[kk], s0, 0, 0, 0);   \
      short8 a1 = *(const short8*)(smem + KR[kk] + (RD) + 4096);               \
      s1 = __builtin_amdgcn_mfma_f32_16x16x32_bf16(a1, qf[kk], s1, 0, 0, 0);   \
    }                                                                          \
    unsigned u0 = pk_bf16(exp2f(s0[0] * SC2), exp2f(s0[1] * SC2));             \
    unsigned u1 = pk_bf16(exp2f(s0[2] * SC2), exp2f(s0[3] * SC2));             \
    unsigned u2 = pk_bf16(exp2f(s1[0] * SC2), exp2f(s1[1] * SC2));             \
    unsigned u3 = pk_bf16(exp2f(s1[2] * SC2), exp2f(s1[3] * SC2));             \
    asm("v_permlane32_swap_b32 %0, %1" : "+v"(u0), "+v"(u2));                  \
    asm("v_permlane32_swap_b32 %0, %1" : "+v"(u1), "+v"(u3));                  \
    asm("v_permlane16_swap_b32 %0, %1" : "+v"(u0), "+v"(u2));                  \
    asm("v_permlane16_swap_b32 %0, %1" : "+v"(u1), "+v"(u3));                  \
    unsigned uu[4] = {u0, u1, u2, u3};                                         \
    short8 pa; __builtin_memcpy(&pa, uu, 16);                                  \
    _Pragma("unroll")                                                          \
    for (int ct = 0; ct < 16; ++ct) {                                          \
      short8 gb = *(const short8*)(smem + GR + (RD) + ct * 1024);              \
      yacc[ct] = __builtin_amdgcn_mfma_f32_16x16x32_bf16(pa, gb, yacc[ct], 0, 0, 0); \
    }                                                                          \
    lacc = __builtin_amdgcn_mfma_f32_16x16x32_bf16(pa, ones, lacc, 0, 0, 0);   \
    __syncthreads();                                                           \
  }

  for (int mt2 = 0; mt2 < MITER / 2; ++mt2) {
    SUBITER(2 * mt2, 0, 24576)
    SUBITER(2 * mt2 + 1, 24576, 0)
  }
#undef SUBITER

  // ---- epilogue: normalize and store out[b][c][n] ----
  float inv[4];
#pragma unroll
  for (int r = 0; r < 4; ++r) inv[r] = 1.0f / lacc[r];
  const int nb = qn0 + wave * 16 + quad * 4;
#pragma unroll
  for (int ct = 0; ct < 16; ++ct) {
    int c = ct * 16 + col;
    float4 v;
    v.x = yacc[ct][0] * inv[0]; v.y = yacc[ct][1] * inv[1];
    v.z = yacc[ct][2] * inv[2]; v.w = yacc[ct][3] * inv[3];
    *(float4*)(out + ((size_t)b * C_IN + c) * N_SP + nb) = v;
  }
}

extern "C" void kernel_launch(void* const* d_in, const int* in_sizes, int n_in,
                              void* d_out, int out_size, void* d_ws, size_t ws_size,
                              hipStream_t stream) {
  const float* x  = (const float*)d_in[0];
  const float* tw = (const float*)d_in[1];
  const float* tb = (const float*)d_in[2];
  const float* pw = (const float*)d_in[3];
  const float* pb = (const float*)d_in[4];
  float* out = (float*)d_out;

  // workspace: Qt (9.4MB) | Kt (9.4MB) | Gbf (18.9MB) = 37.75 MB total
  short* Qt  = (short*)d_ws;
  short* Kt  = Qt + (size_t)B_SZ * N_SP * K_INT;
  short* Gbf = Kt + (size_t)B_SZ * N_SP * K_INT;

  proj_kernel<<<B_SZ * NTILE, 256, 0, stream>>>(x, tw, tb, pw, pb, Qt, Kt, Gbf);
  attn_kernel<<<B_SZ * NTILE, 256, 0, stream>>>(Qt, Kt, Gbf, out);
}

// Round 2
// 257.298 us; speedup vs baseline: 1.2025x; 1.0451x over previous
//
#include <hip/hip_runtime.h>
#include <hip/hip_bf16.h>

#define B_SZ 16
#define C_IN 256
#define N_SP 2304
#define K_INT 128
#define NTILE 36  // q-tiles of 64
#define MT 32     // key/value m-tile
#define MITER 72  // N_SP / MT

typedef __attribute__((ext_vector_type(8))) short short8;
typedef __attribute__((ext_vector_type(4))) float f32x4;

// bf16 weights, converted once by wcvt_kernel: [p][k][c], p=0 theta, p=1 phi
__device__ __align__(16) short g_Wbf[2 * K_INT * C_IN];

// packed fp32x2 -> bf16x2 (v_cvt_pk_bf16_f32, RNE)
__device__ inline unsigned pk_bf16(float a, float b) {
  float2 f; f.x = a; f.y = b;
  __hip_bfloat162 h = __float22bfloat162_rn(f);
  unsigned u;
  __builtin_memcpy(&u, &h, sizeof(u));
  return u;
}

// ---------------------------------------------------------------------------
// One-time weight convert: f32 -> bf16 into g_Wbf (128 KiB, L2-resident).
// ---------------------------------------------------------------------------
__global__ __launch_bounds__(256) void wcvt_kernel(
    const float* __restrict__ tw, const float* __restrict__ pw)
{
  const int i = (blockIdx.x * 256 + threadIdx.x) * 4;  // grid 32 covers 32768
  float4 a = *(const float4*)(tw + i);
  float4 p = *(const float4*)(pw + i);
  uint2 ua; ua.x = pk_bf16(a.x, a.y); ua.y = pk_bf16(a.z, a.w);
  uint2 up; up.x = pk_bf16(p.x, p.y); up.y = pk_bf16(p.z, p.w);
  *(uint2*)(g_Wbf + i) = ua;
  *(uint2*)(g_Wbf + 32768 + i) = up;
}

// ---------------------------------------------------------------------------
// Projection: Qt[b][n][k], Kt[b][n][k] (bf16), Gbf[b][c][n] = bf16(x).
// Weights read pre-converted from g_Wbf (b128 loads, no per-block cvt).
// ---------------------------------------------------------------------------
__global__ __launch_bounds__(256) void proj_kernel(
    const float* __restrict__ x,
    const float* __restrict__ theta_b, const float* __restrict__ phi_b,
    short* __restrict__ Qt, short* __restrict__ Kt, short* __restrict__ Gbf)
{
  __shared__ short Xl[64][264];  // [n][c], +8 pad

  const int b  = blockIdx.x / NTILE;
  const int n0 = (blockIdx.x % NTILE) * 64;
  const int t  = threadIdx.x;  // t == channel c for staging

  // ---- stage: read x row (64 fp32), packed-convert, write Gbf + LDS T ----
  {
    const float* xrow = x + ((size_t)b * C_IN + t) * N_SP + n0;
    unsigned tp[32];
#pragma unroll
    for (int i = 0; i < 16; ++i) {
      float4 v = ((const float4*)xrow)[i];
      tp[2*i]   = pk_bf16(v.x, v.y);
      tp[2*i+1] = pk_bf16(v.z, v.w);
    }
    uint4* grow = (uint4*)(Gbf + ((size_t)b * C_IN + t) * N_SP + n0);
#pragma unroll
    for (int i = 0; i < 8; ++i) {
      uint4 u; u.x = tp[4*i]; u.y = tp[4*i+1]; u.z = tp[4*i+2]; u.w = tp[4*i+3];
      grow[i] = u;
    }
#pragma unroll
    for (int j = 0; j < 32; ++j) {
      Xl[2*j][t]   = (short)tp[j];
      Xl[2*j+1][t] = (short)(tp[j] >> 16);
    }
  }
  __syncthreads();

  const int wave = t >> 6, lane = t & 63;
  const int col = lane & 15, quad = lane >> 4;

  f32x4 acc[2][2][4];
#pragma unroll
  for (int p = 0; p < 2; ++p)
#pragma unroll
    for (int kr = 0; kr < 2; ++kr)
#pragma unroll
      for (int j = 0; j < 4; ++j) {
        acc[p][kr][j][0] = 0.f; acc[p][kr][j][1] = 0.f;
        acc[p][kr][j][2] = 0.f; acc[p][kr][j][3] = 0.f;
      }

#pragma unroll
  for (int cs = 0; cs < 8; ++cs) {
    const int c0 = cs * 32;
    short8 afr[2][2];
#pragma unroll
    for (int p = 0; p < 2; ++p)
#pragma unroll
      for (int kr = 0; kr < 2; ++kr) {
        const int k = wave * 32 + kr * 16 + col;
        afr[p][kr] = *(const short8*)(g_Wbf + p * 32768 + k * C_IN + c0 + quad * 8);
      }
#pragma unroll
    for (int j = 0; j < 4; ++j) {
      short8 bfr = *(const short8*)&Xl[j * 16 + col][c0 + quad * 8];
#pragma unroll
      for (int p = 0; p < 2; ++p)
#pragma unroll
        for (int kr = 0; kr < 2; ++kr)
          acc[p][kr][j] = __builtin_amdgcn_mfma_f32_16x16x32_bf16(
              afr[p][kr], bfr, acc[p][kr][j], 0, 0, 0);
    }
  }

  // ---- epilogue: bias + transpose-store to [b][n][k] bf16 ----
#pragma unroll
  for (int p = 0; p < 2; ++p) {
    const float* bias = p ? phi_b : theta_b;
    short* dst = p ? Kt : Qt;
#pragma unroll
    for (int kr = 0; kr < 2; ++kr) {
      const int k0 = wave * 32 + kr * 16 + quad * 4;
      float4 bv = *(const float4*)(bias + k0);
#pragma unroll
      for (int j = 0; j < 4; ++j) {
        const int n = n0 + j * 16 + col;
        f32x4 v = acc[p][kr][j];
        uint2 sv;
        sv.x = pk_bf16(v[0] + bv.x, v[1] + bv.y);
        sv.y = pk_bf16(v[2] + bv.z, v[3] + bv.w);
        *(uint2*)(dst + ((size_t)b * N_SP + n) * K_INT + k0) = sv;
      }
    }
  }
}

// ---------------------------------------------------------------------------
// Flash attention, m-tile 32.
//  - swapped QK^T (A=K) + permlane -> P A-fragment in registers
//  - c-split PV: wave writes own-q P frag to LDS (1 b128), mid-barrier,
//    then computes all 64 q for its own 64 channels: 4 P-reads + 4 G-reads
//    (vs 16 G-reads). DS ops/wave/iter: 30 -> 23.
//  - K swizzle fixed: f(row)=((row>>1)&7)<<1 distinguishes rows 8 apart
//    (old col&7 left a 4-way chunk conflict = the 5.3e6 residual counter)
//  - l via ones-MFMA per wave; exchanged once through LDS for the epilogue
//  - double-buffered K/G LDS; 2 barriers/iter (mid = P visibility)
// ---------------------------------------------------------------------------
__global__ __launch_bounds__(256) void attn_kernel(
    const short* __restrict__ Qt, const short* __restrict__ Kt,
    const short* __restrict__ Gbf, float* __restrict__ out)
{
  // bytes: A: K[0,8192) G[8192,24576) | B: +24576 | P[49152,53248) | l[53248,53504)
  __shared__ __align__(16) char smem[53504];
  float* l_lds = (float*)(smem + 53248);

  const int b   = blockIdx.x / NTILE;
  const int qn0 = (blockIdx.x % NTILE) * 64;
  const int t = threadIdx.x;
  const int wave = t >> 6, lane = t & 63;
  const int col = lane & 15, quad = lane >> 4;

  const short* Ktb = Kt  + (size_t)b * N_SP * K_INT;
  const short* Gb  = Gbf + (size_t)b * C_IN * N_SP;

  // Q fragments in registers for the whole loop (B-operand layout: col=q)
  short8 qf[4];
  {
    const short* qb = Qt + ((size_t)b * N_SP + qn0 + wave * 16 + col) * K_INT + quad * 8;
#pragma unroll
    for (int kk = 0; kk < 4; ++kk) qf[kk] = *(const short8*)(qb + kk * 32);
  }

  f32x4 yacc[4][4];  // [q-tile][c-tile]
#pragma unroll
  for (int i = 0; i < 4; ++i)
#pragma unroll
    for (int j = 0; j < 4; ++j) {
      yacc[i][j][0] = 0.f; yacc[i][j][1] = 0.f;
      yacc[i][j][2] = 0.f; yacc[i][j][3] = 0.f;
    }
  f32x4 lacc;
  lacc[0] = 0.f; lacc[1] = 0.f; lacc[2] = 0.f; lacc[3] = 0.f;

  short8 ones;
#pragma unroll
  for (int j = 0; j < 8; ++j) ones[j] = (short)0x3F80;  // bf16 1.0

  const float SC2 = 0.12754859f;  // (1/sqrt(128)) * log2(e)

  // ---- LDS byte offsets (loop-invariant; swizzle folded into base) ----
  // K tile [32][128] bf16, 16B-chunk swizzle: phys = chunk ^ (((row>>1)&7)<<1)
  const int KW = (t >> 4) * 256 + (((t & 15) ^ ((((t >> 5) & 7)) << 1)) << 4);
  // G tile [256][32] bf16, 16B-chunk swizzle: phys = chunk ^ ((row>>1)&3)
  const int GW = 8192 + (t >> 2) * 64 + ((((t & 3) ^ ((t >> 3) & 3))) << 4);
  int KR[4];
#pragma unroll
  for (int kk = 0; kk < 4; ++kk)
    KR[kk] = col * 256 + ((((kk << 2) + quad) ^ ((((col >> 1) & 7)) << 1)) << 4);
  // G read: own 64-channel range, rows wave*64 + ct*16 + col
  const int GR = 8192 + wave * 4096 + col * 64 + ((quad ^ ((col >> 1) & 3)) << 4);
  // P buffer: [64 q][32 m] bf16, no swizzle needed (row stride 64 B)
  const int PW = 49152 + wave * 1024 + col * 64 + quad * 16;
  const int PR = 49152 + col * 64 + quad * 16;

  // ---- global staging offsets ----
  const int koff = (t >> 4) * K_INT + (t & 15) * 8;  // K rows t>>4 / +16
  const int goff = (t >> 2) * N_SP + (t & 3) * 8;    // G rows t>>2 (+64i)

  short8 pre[6];
  // stage tile 0 -> buffer A
  pre[0] = *(const short8*)(Ktb + koff);
  pre[1] = *(const short8*)(Ktb + 2048 + koff);
#pragma unroll
  for (int i = 0; i < 4; ++i) pre[2 + i] = *(const short8*)(Gb + i * 64 * N_SP + goff);
  *(short8*)(smem + KW) = pre[0];
  *(short8*)(smem + KW + 4096) = pre[1];
#pragma unroll
  for (int i = 0; i < 4; ++i) *(short8*)(smem + GW + i * 4096) = pre[2 + i];
  // issue tile 1 loads
  pre[0] = *(const short8*)(Ktb + 4096 + koff);
  pre[1] = *(const short8*)(Ktb + 6144 + koff);
#pragma unroll
  for (int i = 0; i < 4; ++i) pre[2 + i] = *(const short8*)(Gb + 32 + i * 64 * N_SP + goff);
  const short* kptr = Ktb + 8192 + koff;  // tile 2
  const short* gptr = Gb + 64 + goff;     // tile 2
  __syncthreads();

#define SUBITER(MTV, RD, WR)                                                   \
  {                                                                            \
    if ((MTV) + 1 < MITER) {                                                   \
      *(short8*)(smem + KW + (WR)) = pre[0];                                   \
      *(short8*)(smem + KW + (WR) + 4096) = pre[1];                            \
      _Pragma("unroll")                                                        \
      for (int i = 0; i < 4; ++i)                                              \
        *(short8*)(smem + GW + (WR) + i * 4096) = pre[2 + i];                  \
      if ((MTV) + 2 < MITER) {                                                 \
        pre[0] = *(const short8*)(kptr);                                       \
        pre[1] = *(const short8*)(kptr + 2048);                                \
        _Pragma("unroll")                                                      \
        for (int i = 0; i < 4; ++i)                                            \
          pre[2 + i] = *(const short8*)(gptr + i * 64 * N_SP);                 \
        kptr += 4096; gptr += 32;                                              \
      }                                                                        \
    }                                                                          \
    f32x4 s0, s1;                                                              \
    s0[0] = 0.f; s0[1] = 0.f; s0[2] = 0.f; s0[3] = 0.f;                        \
    s1[0] = 0.f; s1[1] = 0.f; s1[2] = 0.f; s1[3] = 0.f;                        \
    _Pragma("unroll")                                                          \
    for (int kk = 0; kk < 4; ++kk) {                                           \
      short8 a0 = *(const short8*)(smem + KR[kk] + (RD));                      \
      s0 = __builtin_amdgcn_mfma_f32_16x16x32_bf16(a0, qf[kk], s0, 0, 0, 0);   \
      short8 a1 = *(const short8*)(smem + KR[kk] + (RD) + 4096);               \
      s1 = __builtin_amdgcn_mfma_f32_16x16x32_bf16(a1, qf[kk], s1, 0, 0, 0);   \
    }                                                                          \
    unsigned u0 = pk_bf16(exp2f(s0[0] * SC2), exp2f(s0[1] * SC2));             \
    unsigned u1 = pk_bf16(exp2f(s0[2] * SC2), exp2f(s0[3] * SC2));             \
    unsigned u2 = pk_bf16(exp2f(s1[0] * SC2), exp2f(s1[1] * SC2));             \
    unsigned u3 = pk_bf16(exp2f(s1[2] * SC2), exp2f(s1[3] * SC2));             \
    asm("v_permlane32_swap_b32 %0, %1" : "+v"(u0), "+v"(u2));                  \
    asm("v_permlane32_swap_b32 %0, %1" : "+v"(u1), "+v"(u3));                  \
    asm("v_permlane16_swap_b32 %0, %1" : "+v"(u0), "+v"(u2));                  \
    asm("v_permlane16_swap_b32 %0, %1" : "+v"(u1), "+v"(u3));                  \
    unsigned uu[4] = {u0, u1, u2, u3};                                         \
    short8 pa; __builtin_memcpy(&pa, uu, 16);                                  \
    lacc = __builtin_amdgcn_mfma_f32_16x16x32_bf16(pa, ones, lacc, 0, 0, 0);   \
    *(short8*)(smem + PW) = pa;                                                \
    __syncthreads(); /* P visible to all waves */                              \
    short8 paq[4];                                                             \
    _Pragma("unroll")                                                          \
    for (int qt = 0; qt < 4; ++qt)                                             \
      paq[qt] = *(const short8*)(smem + PR + qt * 1024);                       \
    _Pragma("unroll")                                                          \
    for (int ct = 0; ct < 4; ++ct) {                                           \
      short8 gb = *(const short8*)(smem + GR + (RD) + ct * 1024);              \
      _Pragma("unroll")                                                        \
      for (int qt = 0; qt < 4; ++qt)                                           \
        yacc[qt][ct] = __builtin_amdgcn_mfma_f32_16x16x32_bf16(                \
            paq[qt], gb, yacc[qt][ct], 0, 0, 0);                               \
    }                                                                          \
    __syncthreads(); /* epoch end: K/G/P reads done before rewrites */         \
  }

  for (int mt2 = 0; mt2 < MITER / 2; ++mt2) {
    SUBITER(2 * mt2, 0, 24576)
    SUBITER(2 * mt2 + 1, 24576, 0)
  }
#undef SUBITER

  // ---- l exchange: wave w holds l[16w + quad*4 + r] in lacc[r] ----
  if (col == 0) {
#pragma unroll
    for (int r = 0; r < 4; ++r) l_lds[wave * 16 + quad * 4 + r] = lacc[r];
  }
  __syncthreads();

  // ---- epilogue: normalize and store out[b][c][n]; c = wave*64+ct*16+col ----
#pragma unroll
  for (int qt = 0; qt < 4; ++qt) {
    float4 lq = *(const float4*)&l_lds[qt * 16 + quad * 4];
    float4 iv;
    iv.x = 1.0f / lq.x; iv.y = 1.0f / lq.y; iv.z = 1.0f / lq.z; iv.w = 1.0f / lq.w;
    const int nb = qn0 + qt * 16 + quad * 4;
#pragma unroll
    for (int ct = 0; ct < 4; ++ct) {
      const int c = wave * 64 + ct * 16 + col;
      f32x4 v = yacc[qt][ct];
      float4 o;
      o.x = v[0] * iv.x; o.y = v[1] * iv.y; o.z = v[2] * iv.z; o.w = v[3] * iv.w;
      *(float4*)(out + ((size_t)b * C_IN + c) * N_SP + nb) = o;
    }
  }
}

extern "C" void kernel_launch(void* const* d_in, const int* in_sizes, int n_in,
                              void* d_out, int out_size, void* d_ws, size_t ws_size,
                              hipStream_t stream) {
  const float* x  = (const float*)d_in[0];
  const float* tw = (const float*)d_in[1];
  const float* tb = (const float*)d_in[2];
  const float* pw = (const float*)d_in[3];
  const float* pb = (const float*)d_in[4];
  float* out = (float*)d_out;

  // workspace: Qt (9.4MB) | Kt (9.4MB) | Gbf (18.9MB) = 37.75 MB total
  short* Qt  = (short*)d_ws;
  short* Kt  = Qt + (size_t)B_SZ * N_SP * K_INT;
  short* Gbf = Kt + (size_t)B_SZ * N_SP * K_INT;

  wcvt_kernel<<<32, 256, 0, stream>>>(tw, pw);
  proj_kernel<<<B_SZ * NTILE, 256, 0, stream>>>(x, tb, pb, Qt, Kt, Gbf);
  attn_kernel<<<B_SZ * NTILE, 256, 0, stream>>>(Qt, Kt, Gbf, out);
}